// Round 6
// baseline (6662.999 us; speedup 1.0000x reference)
//
#include <hip/hip_runtime.h>
#include <math.h>

typedef unsigned short u16;
typedef unsigned int u32;

#define D_EMB 768
#define F_HID 3072
#define N_TOK 4096
#define N_PAIR 8192
#define GATE_TH 1e-9f
#define XSTR 776      // padded LDS stride for x rows (u16)
#define HSTR 3080     // padded LDS stride for h rows (u16)
#define BM 8          // pairs per block

__device__ inline float b2f(u16 u) {
    union { float f; u32 i; } c; c.i = ((u32)u) << 16; return c.f;
}
__device__ inline u16 f2b(float f) {
    union { float f; u32 i; } c; c.f = f;
    u32 r = c.i + 0x7FFFu + ((c.i >> 16) & 1u);   // round-nearest-even
    return (u16)(r >> 16);
}

// ---------------------------------------------------------------- dtype detect
// Even u16s of x: bf16-world = actual x values (|v|<=~5); fp32-world = low
// mantissa halves (uniform bits -> ~48% decode to |v|>100 or NaN).
__global__ void moe_detect_kernel(const u16* __restrict__ xr, int* __restrict__ flag) {
    __shared__ int tot;
    if (threadIdx.x == 0) tot = 0;
    __syncthreads();
    int c = 0;
    for (int j = 0; j < 8; j++) {
        u16 u = xr[2 * (threadIdx.x * 8 + j)];
        float v = b2f(u);
        if (!(fabsf(v) <= 100.f)) c++;       // catches NaN too
    }
    atomicAdd(&tot, c);
    __syncthreads();
    if (threadIdx.x == 0) flag[0] = (tot > 64) ? 1 : 0;   // 1 = fp32 inputs
}

// ---------------------------------------------------------------- init
__global__ void moe_init_kernel(int* __restrict__ cnt) {
    if (threadIdx.x < 8) cnt[threadIdx.x] = 0;
}

// ---------------------------------------------------------------- zero out
__global__ __launch_bounds__(256) void moe_zero_kernel(
    const int* __restrict__ flag, int want, uint4* __restrict__ out) {
    if (flag[0] != want) return;
    int i = blockIdx.x * 256 + threadIdx.x;
    out[i] = make_uint4(0, 0, 0, 0);
}

// ---------------------------------------------------------------- router (bf16)
__global__ __launch_bounds__(256) void moe_router_b16(
    const int* __restrict__ flag,
    const u16* __restrict__ x, const u16* __restrict__ noise,
    const u16* __restrict__ Wg, const u16* __restrict__ bg,
    const u16* __restrict__ Wn, const u16* __restrict__ bn,
    int* __restrict__ tk_e, float* __restrict__ tk_g, int* __restrict__ cnt)
{
    if (flag[0] != 0) return;
    const int t = blockIdx.x * 4 + (threadIdx.x >> 6);
    const int lane = threadIdx.x & 63;
    float ag[8] = {}, an[8] = {};
    for (int i = 0; i < 12; i++) {
        int k = i * 64 + lane;
        float xv = b2f(x[(size_t)t * D_EMB + k]);
        const u16* wgp = Wg + k * 8;
        const u16* wnp = Wn + k * 8;
#pragma unroll
        for (int e = 0; e < 8; e++) {
            ag[e] += xv * b2f(wgp[e]);
            an[e] += xv * b2f(wnp[e]);
        }
    }
#pragma unroll
    for (int e = 0; e < 8; e++) {
        float vg = ag[e], vn = an[e];
        for (int s = 32; s; s >>= 1) { vg += __shfl_xor(vg, s); vn += __shfl_xor(vn, s); }
        ag[e] = vg; an[e] = vn;
    }
    if (lane == 0) {
        float best = -INFINITY, sec = -INFINITY; int be = 0, se = 0;
#pragma unroll
        for (int e = 0; e < 8; e++) {
            float nl = an[e] + b2f(bn[e]);
            float sp = nl > 0.f ? nl + log1pf(expf(-nl)) : log1pf(expf(nl));
            float v = ag[e] + b2f(bg[e]) + b2f(noise[(size_t)t * 8 + e]) * sp;
            if (v > best) { sec = best; se = be; best = v; be = e; }
            else if (v > sec) { sec = v; se = e; }
        }
        float ex = expf(sec - best);
        float g1 = 1.f / (1.f + ex), g2 = ex / (1.f + ex);
        tk_e[t * 2 + 0] = (g1 > GATE_TH) ? be : -1; tk_g[t * 2 + 0] = g1;
        tk_e[t * 2 + 1] = (g2 > GATE_TH) ? se : -1; tk_g[t * 2 + 1] = g2;
        if (g1 > GATE_TH) atomicAdd(&cnt[be], 1);
        if (g2 > GATE_TH) atomicAdd(&cnt[se], 1);
    }
}

// ---------------------------------------------------------------- router (fp32)
__global__ __launch_bounds__(256) void moe_router_f32(
    const int* __restrict__ flag,
    const float* __restrict__ x, const float* __restrict__ noise,
    const float* __restrict__ Wg, const float* __restrict__ bg,
    const float* __restrict__ Wn, const float* __restrict__ bn,
    int* __restrict__ tk_e, float* __restrict__ tk_g, int* __restrict__ cnt)
{
    if (flag[0] != 1) return;
    const int t = blockIdx.x * 4 + (threadIdx.x >> 6);
    const int lane = threadIdx.x & 63;
    float ag[8] = {}, an[8] = {};
    for (int i = 0; i < 12; i++) {
        int k = i * 64 + lane;
        float xv = x[(size_t)t * D_EMB + k];
        const float* wgp = Wg + k * 8;
        const float* wnp = Wn + k * 8;
#pragma unroll
        for (int e = 0; e < 8; e++) {
            ag[e] += xv * wgp[e];
            an[e] += xv * wnp[e];
        }
    }
#pragma unroll
    for (int e = 0; e < 8; e++) {
        float vg = ag[e], vn = an[e];
        for (int s = 32; s; s >>= 1) { vg += __shfl_xor(vg, s); vn += __shfl_xor(vn, s); }
        ag[e] = vg; an[e] = vn;
    }
    if (lane == 0) {
        float best = -INFINITY, sec = -INFINITY; int be = 0, se = 0;
#pragma unroll
        for (int e = 0; e < 8; e++) {
            float nl = an[e] + bn[e];
            float sp = nl > 0.f ? nl + log1pf(expf(-nl)) : log1pf(expf(nl));
            float v = ag[e] + bg[e] + noise[(size_t)t * 8 + e] * sp;
            if (v > best) { sec = best; se = be; best = v; be = e; }
            else if (v > sec) { sec = v; se = e; }
        }
        float ex = expf(sec - best);
        float g1 = 1.f / (1.f + ex), g2 = ex / (1.f + ex);
        tk_e[t * 2 + 0] = (g1 > GATE_TH) ? be : -1; tk_g[t * 2 + 0] = g1;
        tk_e[t * 2 + 1] = (g2 > GATE_TH) ? se : -1; tk_g[t * 2 + 1] = g2;
        if (g1 > GATE_TH) atomicAdd(&cnt[be], 1);
        if (g2 > GATE_TH) atomicAdd(&cnt[se], 1);
    }
}

// ---------------------------------------------------------------- offsets / scatter
__global__ void moe_offsets_kernel(const int* __restrict__ cnt,
                                   int* __restrict__ off, int* __restrict__ cursor) {
    if (threadIdx.x == 0) {
        int s = 0;
        for (int e = 0; e < 8; e++) { off[e] = s; cursor[e] = s; s += cnt[e]; }
    }
}

__global__ void moe_scatter_kernel(const int* __restrict__ tk_e, const float* __restrict__ tk_g,
                                   int* __restrict__ cursor, int* __restrict__ plist,
                                   float* __restrict__ pg) {
    int i = blockIdx.x * 256 + threadIdx.x;
    if (i < N_PAIR) {
        int e = tk_e[i];
        if (e >= 0) {
            int p = atomicAdd(&cursor[e], 1);
            plist[p] = i >> 1;
            pg[p] = tk_g[i];
        }
    }
}

// ---------------------------------------------------------------- fused FFN (bf16)
__global__ __launch_bounds__(256) void moe_ffn_fused_b16(
    const int* __restrict__ flag,
    const u16* __restrict__ x,
    const u16* __restrict__ w1, const u16* __restrict__ b1,
    const u16* __restrict__ w2, const u16* __restrict__ b2,
    const int* __restrict__ plist, const float* __restrict__ pg,
    const int* __restrict__ cnt, const int* __restrict__ off,
    u16* __restrict__ out)
{
    if (flag[0] != 0) return;
    __shared__ __align__(16) u16 xs[BM * XSTR];
    __shared__ __align__(16) u16 hs[BM * HSTR];
    const int e = blockIdx.x;
    const int Cl = cnt[e];
    if (Cl <= 0) return;
    const int O = off[e];
    const int tid = threadIdx.x;

    for (int t0 = blockIdx.y * BM; t0 < Cl; t0 += gridDim.y * BM) {
        for (int ci = tid; ci < BM * 96; ci += 256) {
            int row = ci / 96, c = ci - row * 96;
            uint4 v = make_uint4(0, 0, 0, 0);
            if (t0 + row < Cl) {
                int tok = plist[O + t0 + row];
                v = *(const uint4*)(x + (size_t)tok * D_EMB + c * 8);
            }
            *(uint4*)(&xs[row * XSTR + c * 8]) = v;
        }
        __syncthreads();

        for (int wi = tid; wi < BM * 384; wi += 256) {
            int row = wi / 384, nc = wi - row * 384;
            int n0 = nc * 8;
            float a[8] = {};
            const u16* wp = w1 + (size_t)e * D_EMB * F_HID + n0;
            const u16* xr = &xs[row * XSTR];
            for (int k = 0; k < D_EMB; k++) {
                uint4 wv = *(const uint4*)(wp + (size_t)k * F_HID);
                float xv = b2f(xr[k]);
                a[0] += xv * b2f((u16)(wv.x & 0xFFFFu)); a[1] += xv * b2f((u16)(wv.x >> 16));
                a[2] += xv * b2f((u16)(wv.y & 0xFFFFu)); a[3] += xv * b2f((u16)(wv.y >> 16));
                a[4] += xv * b2f((u16)(wv.z & 0xFFFFu)); a[5] += xv * b2f((u16)(wv.z >> 16));
                a[6] += xv * b2f((u16)(wv.w & 0xFFFFu)); a[7] += xv * b2f((u16)(wv.w >> 16));
            }
            const u16* bp = b1 + e * F_HID + n0;
            u16* hp = &hs[row * HSTR + n0];
#pragma unroll
            for (int j = 0; j < 8; j++) {
                float v = a[j] + b2f(bp[j]);
                hp[j] = f2b(v > 0.f ? v : 0.f);
            }
        }
        __syncthreads();

        for (int wi = tid; wi < BM * 96; wi += 256) {
            int row = wi / 96, nc = wi - row * 96;
            int n0 = nc * 8;
            float a[8] = {};
            const u16* wp = w2 + (size_t)e * F_HID * D_EMB + n0;
            const u16* hr = &hs[row * HSTR];
            for (int k = 0; k < F_HID; k++) {
                uint4 wv = *(const uint4*)(wp + (size_t)k * D_EMB);
                float hv = b2f(hr[k]);
                a[0] += hv * b2f((u16)(wv.x & 0xFFFFu)); a[1] += hv * b2f((u16)(wv.x >> 16));
                a[2] += hv * b2f((u16)(wv.y & 0xFFFFu)); a[3] += hv * b2f((u16)(wv.y >> 16));
                a[4] += hv * b2f((u16)(wv.z & 0xFFFFu)); a[5] += hv * b2f((u16)(wv.z >> 16));
                a[6] += hv * b2f((u16)(wv.w & 0xFFFFu)); a[7] += hv * b2f((u16)(wv.w >> 16));
            }
            if (t0 + row < Cl) {
                int p = O + t0 + row;
                int tok = plist[p];
                float g = pg[p];
                const u16* bp = b2 + e * D_EMB + n0;
#pragma unroll
                for (int j = 0; j < 8; j++) {
                    int gcol = n0 + j;
                    float add = g * (a[j] + b2f(bp[j]));
                    u32* wpd = (u32*)(out + ((size_t)tok * D_EMB + (gcol & ~1)));
                    const bool hi16 = (gcol & 1);
                    u32 oldv = *wpd, assumed;
                    do {
                        assumed = oldv;
                        u16 cur = hi16 ? (u16)(assumed >> 16) : (u16)(assumed & 0xFFFFu);
                        u16 neu = f2b(b2f(cur) + add);
                        u32 nv = hi16 ? ((assumed & 0x0000FFFFu) | ((u32)neu << 16))
                                      : ((assumed & 0xFFFF0000u) | (u32)neu);
                        oldv = atomicCAS(wpd, assumed, nv);
                    } while (oldv != assumed);
                }
            }
        }
        __syncthreads();
    }
}

// ---------------------------------------------------------------- fused FFN (fp32)
// fp32 weights/biases/output; x and h staged as bf16 in LDS (error ~1e-3 rel).
__global__ __launch_bounds__(256) void moe_ffn_fused_f32(
    const int* __restrict__ flag,
    const float* __restrict__ x,
    const float* __restrict__ w1, const float* __restrict__ b1,
    const float* __restrict__ w2, const float* __restrict__ b2,
    const int* __restrict__ plist, const float* __restrict__ pg,
    const int* __restrict__ cnt, const int* __restrict__ off,
    float* __restrict__ out)
{
    if (flag[0] != 1) return;
    __shared__ __align__(16) u16 xs[BM * XSTR];
    __shared__ __align__(16) u16 hs[BM * HSTR];
    const int e = blockIdx.x;
    const int Cl = cnt[e];
    if (Cl <= 0) return;
    const int O = off[e];
    const int tid = threadIdx.x;

    for (int t0 = blockIdx.y * BM; t0 < Cl; t0 += gridDim.y * BM) {
        // stage x rows -> bf16 LDS (8 rows x 192 float4-chunks)
        for (int ci = tid; ci < BM * 192; ci += 256) {
            int row = ci / 192, c = ci - row * 192;
            float4 v = make_float4(0.f, 0.f, 0.f, 0.f);
            if (t0 + row < Cl) {
                int tok = plist[O + t0 + row];
                v = *(const float4*)(x + (size_t)tok * D_EMB + c * 4);
            }
            u16* d = &xs[row * XSTR + c * 4];
            d[0] = f2b(v.x); d[1] = f2b(v.y); d[2] = f2b(v.z); d[3] = f2b(v.w);
        }
        __syncthreads();

        // FFN1: 8 rows x 768 4-col chunks
        for (int wi = tid; wi < BM * 768; wi += 256) {
            int row = wi / 768, nc = wi - row * 768;
            int n0 = nc * 4;
            float a0 = 0, a1 = 0, a2 = 0, a3 = 0;
            const float* wp = w1 + (size_t)e * D_EMB * F_HID + n0;
            const u16* xr = &xs[row * XSTR];
            for (int k = 0; k < D_EMB; k++) {
                float4 wv = *(const float4*)(wp + (size_t)k * F_HID);
                float xv = b2f(xr[k]);
                a0 += xv * wv.x; a1 += xv * wv.y; a2 += xv * wv.z; a3 += xv * wv.w;
            }
            const float* bp = b1 + (size_t)e * F_HID + n0;
            u16* hp = &hs[row * HSTR + n0];
            float v;
            v = a0 + bp[0]; hp[0] = f2b(v > 0.f ? v : 0.f);
            v = a1 + bp[1]; hp[1] = f2b(v > 0.f ? v : 0.f);
            v = a2 + bp[2]; hp[2] = f2b(v > 0.f ? v : 0.f);
            v = a3 + bp[3]; hp[3] = f2b(v > 0.f ? v : 0.f);
        }
        __syncthreads();

        // FFN2: 8 rows x 192 4-col chunks
        for (int wi = tid; wi < BM * 192; wi += 256) {
            int row = wi / 192, nc = wi - row * 192;
            int n0 = nc * 4;
            float a0 = 0, a1 = 0, a2 = 0, a3 = 0;
            const float* wp = w2 + (size_t)e * F_HID * D_EMB + n0;
            const u16* hr = &hs[row * HSTR];
            for (int k = 0; k < F_HID; k++) {
                float4 wv = *(const float4*)(wp + (size_t)k * D_EMB);
                float hv = b2f(hr[k]);
                a0 += hv * wv.x; a1 += hv * wv.y; a2 += hv * wv.z; a3 += hv * wv.w;
            }
            if (t0 + row < Cl) {
                int p = O + t0 + row;
                int tok = plist[p];
                float g = pg[p];
                const float* bp = b2 + (size_t)e * D_EMB + n0;
                float* op = out + (size_t)tok * D_EMB + n0;
                atomicAdd(&op[0], g * (a0 + bp[0]));
                atomicAdd(&op[1], g * (a1 + bp[1]));
                atomicAdd(&op[2], g * (a2 + bp[2]));
                atomicAdd(&op[3], g * (a3 + bp[3]));
            }
        }
        __syncthreads();
    }
}

// ---------------------------------------------------------------- launch
extern "C" void kernel_launch(void* const* d_in, const int* in_sizes, int n_in,
                              void* d_out, int out_size, void* d_ws, size_t ws_size,
                              hipStream_t stream) {
    // workspace: 132 KB metadata
    char* ws = (char*)d_ws;
    int*   cnt    = (int*)(ws + 0);
    int*   off    = (int*)(ws + 256);
    int*   cursor = (int*)(ws + 512);
    int*   flag   = (int*)(ws + 768);
    int*   tk_e   = (int*)(ws + 1024);      // 32768 B
    float* tk_g   = (float*)(ws + 33792);   // 32768 B
    int*   plist  = (int*)(ws + 66560);     // 32768 B
    float* pg     = (float*)(ws + 99328);   // 32768 B

    moe_init_kernel<<<dim3(1), dim3(64), 0, stream>>>(cnt);
    moe_detect_kernel<<<dim3(1), dim3(256), 0, stream>>>((const u16*)d_in[0], flag);

    // zero d_out: bf16 world = 6.29 MB (1536 blocks), fp32 world = 12.58 MB (3072)
    moe_zero_kernel<<<dim3(1536), dim3(256), 0, stream>>>(flag, 0, (uint4*)d_out);
    moe_zero_kernel<<<dim3(3072), dim3(256), 0, stream>>>(flag, 1, (uint4*)d_out);

    moe_router_b16<<<dim3(N_TOK / 4), dim3(256), 0, stream>>>(
        flag, (const u16*)d_in[0], (const u16*)d_in[1], (const u16*)d_in[2],
        (const u16*)d_in[3], (const u16*)d_in[4], (const u16*)d_in[5],
        tk_e, tk_g, cnt);
    moe_router_f32<<<dim3(N_TOK / 4), dim3(256), 0, stream>>>(
        flag, (const float*)d_in[0], (const float*)d_in[1], (const float*)d_in[2],
        (const float*)d_in[3], (const float*)d_in[4], (const float*)d_in[5],
        tk_e, tk_g, cnt);

    moe_offsets_kernel<<<dim3(1), dim3(64), 0, stream>>>(cnt, off, cursor);
    moe_scatter_kernel<<<dim3(N_PAIR / 256), dim3(256), 0, stream>>>(
        tk_e, tk_g, cursor, plist, pg);

    moe_ffn_fused_b16<<<dim3(8, 192), dim3(256), 0, stream>>>(
        flag, (const u16*)d_in[0], (const u16*)d_in[6], (const u16*)d_in[7],
        (const u16*)d_in[8], (const u16*)d_in[9], plist, pg, cnt, off,
        (u16*)d_out);
    moe_ffn_fused_f32<<<dim3(8, 192), dim3(256), 0, stream>>>(
        flag, (const float*)d_in[0], (const float*)d_in[6], (const float*)d_in[7],
        (const float*)d_in[8], (const float*)d_in[9], plist, pg, cnt, off,
        (float*)d_out);
    (void)in_sizes; (void)n_in; (void)out_size; (void)ws_size;
}

// Round 7
// 598.994 us; speedup vs baseline: 11.1236x; 11.1236x over previous
//
#include <hip/hip_runtime.h>
#include <math.h>

typedef unsigned short u16;
typedef unsigned int u32;

#define D_EMB 768
#define F_HID 3072
#define N_TOK 4096
#define N_PAIR 8192
#define GATE_TH 1e-9f

typedef float f32x4 __attribute__((ext_vector_type(4)));
typedef __bf16 bfrag __attribute__((ext_vector_type(8)));

__device__ inline float b2f(u16 u) {
    union { float f; u32 i; } c; c.i = ((u32)u) << 16; return c.f;
}
__device__ inline u16 f2b(float f) {
    union { float f; u32 i; } c; c.f = f;
    u32 r = c.i + 0x7FFFu + ((c.i >> 16) & 1u);   // round-nearest-even
    return (u16)(r >> 16);
}
__device__ inline f32x4 mfma16(bfrag a, bfrag b, f32x4 c) {
    return __builtin_amdgcn_mfma_f32_16x16x32_bf16(a, b, c, 0, 0, 0);
}

// ---------------------------------------------------------------- init / zero
__global__ void moe_init_kernel(int* __restrict__ cnt) {
    if (threadIdx.x < 8) cnt[threadIdx.x] = 0;
}
__global__ __launch_bounds__(256) void moe_zero_kernel(uint4* __restrict__ out) {
    int i = blockIdx.x * 256 + threadIdx.x;   // 786432 uint4 = 12.58 MB (fp32 out)
    out[i] = make_uint4(0, 0, 0, 0);
}

// ---------------------------------------------------------------- router (fp32)
__global__ __launch_bounds__(256) void moe_router_f32(
    const float* __restrict__ x, const float* __restrict__ noise,
    const float* __restrict__ Wg, const float* __restrict__ bg,
    const float* __restrict__ Wn, const float* __restrict__ bn,
    int* __restrict__ tk_e, float* __restrict__ tk_g, int* __restrict__ cnt)
{
    const int t = blockIdx.x * 4 + (threadIdx.x >> 6);
    const int lane = threadIdx.x & 63;
    float ag[8] = {}, an[8] = {};
    for (int i = 0; i < 12; i++) {
        int k = i * 64 + lane;
        float xv = x[(size_t)t * D_EMB + k];
        const float* wgp = Wg + k * 8;
        const float* wnp = Wn + k * 8;
#pragma unroll
        for (int e = 0; e < 8; e++) {
            ag[e] += xv * wgp[e];
            an[e] += xv * wnp[e];
        }
    }
#pragma unroll
    for (int e = 0; e < 8; e++) {
        float vg = ag[e], vn = an[e];
        for (int s = 32; s; s >>= 1) { vg += __shfl_xor(vg, s); vn += __shfl_xor(vn, s); }
        ag[e] = vg; an[e] = vn;
    }
    if (lane == 0) {
        float best = -INFINITY, sec = -INFINITY; int be = 0, se = 0;
#pragma unroll
        for (int e = 0; e < 8; e++) {
            float nl = an[e] + bn[e];
            float sp = nl > 0.f ? nl + log1pf(expf(-nl)) : log1pf(expf(nl));  // softplus
            float v = ag[e] + bg[e] + noise[(size_t)t * 8 + e] * sp;
            if (v > best) { sec = best; se = be; best = v; be = e; }
            else if (v > sec) { sec = v; se = e; }
        }
        float ex = expf(sec - best);
        float g1 = 1.f / (1.f + ex), g2 = ex / (1.f + ex);
        tk_e[t * 2 + 0] = (g1 > GATE_TH) ? be : -1; tk_g[t * 2 + 0] = g1;
        tk_e[t * 2 + 1] = (g2 > GATE_TH) ? se : -1; tk_g[t * 2 + 1] = g2;
        if (g1 > GATE_TH) atomicAdd(&cnt[be], 1);
        if (g2 > GATE_TH) atomicAdd(&cnt[se], 1);
    }
}

// ---------------------------------------------------------------- offsets / scatter
__global__ void moe_offsets_kernel(const int* __restrict__ cnt,
                                   int* __restrict__ off, int* __restrict__ cursor) {
    if (threadIdx.x == 0) {
        int s = 0;
        for (int e = 0; e < 8; e++) { off[e] = s; cursor[e] = s; s += cnt[e]; }
    }
}
__global__ void moe_scatter_kernel(const int* __restrict__ tk_e, const float* __restrict__ tk_g,
                                   int* __restrict__ cursor, int* __restrict__ plist,
                                   float* __restrict__ pg) {
    int i = blockIdx.x * 256 + threadIdx.x;
    if (i < N_PAIR) {
        int e = tk_e[i];
        if (e >= 0) {
            int p = atomicAdd(&cursor[e], 1);
            plist[p] = i >> 1;
            pg[p] = tk_g[i];
        }
    }
}

// ---------------------------------------------------------------- transpose+convert
// in fp32 [Z][R][C] -> out bf16 [Z][C][R]
__global__ __launch_bounds__(256) void moe_transcvt_kernel(
    const float* __restrict__ in, u16* __restrict__ out, int R, int C) {
    __shared__ float tile[32][33];
    const int z = blockIdx.z;
    const int c0 = blockIdx.x * 32, r0 = blockIdx.y * 32;
    const int tx = threadIdx.x & 31, ty = threadIdx.x >> 5;   // ty 0..7
    const size_t base = (size_t)z * R * C;
#pragma unroll
    for (int j = 0; j < 32; j += 8)
        tile[ty + j][tx] = in[base + (size_t)(r0 + ty + j) * C + c0 + tx];
    __syncthreads();
#pragma unroll
    for (int j = 0; j < 32; j += 8)
        out[base + (size_t)(c0 + ty + j) * R + r0 + tx] = f2b(tile[tx][ty + j]);
}

// ---------------------------------------------------------------- FFN1 GEMM
// h[p-P0] = relu(bf16(x[plist[p]]) . w1t[e]^T + b1[e]); 128x128x32 tiles, 4 waves.
__global__ __launch_bounds__(256) void moe_ffn1_kernel(
    const float* __restrict__ x, const u16* __restrict__ w1t, const float* __restrict__ b1,
    const int* __restrict__ plist, const int* __restrict__ cnt, const int* __restrict__ off,
    u16* __restrict__ h, int P0, int P1)
{
    __shared__ __align__(16) u16 As[128 * 32];
    __shared__ __align__(16) u16 Bs[128 * 32];
    const int e = blockIdx.z;
    int lo = off[e], hi = lo + cnt[e];
    if (lo < P0) lo = P0;
    if (hi > P1) hi = P1;
    const int Cl = hi - lo;
    if (Cl <= 0) return;
    const int n0 = blockIdx.x * 128;
    const int tid = threadIdx.x;
    const int lane = tid & 63, wave = tid >> 6;
    const int wr = wave >> 1, wc = wave & 1;
    const int q = lane >> 4, r = lane & 15;
    const int srow = tid >> 1, shalf = tid & 1;   // staging: row 0..127, 16-elem half

    const u16* brow = w1t + ((size_t)e * F_HID + n0 + srow) * D_EMB + shalf * 16;

    for (int m0 = blockIdx.y * 128; m0 < Cl; m0 += gridDim.y * 128) {
        f32x4 acc[4][4] = {};
        const bool vrow = (m0 + srow) < Cl;
        int tok = 0;
        if (vrow) tok = plist[lo + m0 + srow];
        const float* xrow = x + (size_t)tok * D_EMB + shalf * 16;

        for (int k0 = 0; k0 < D_EMB; k0 += 32) {
            u16 tmp[16];
            if (vrow) {
#pragma unroll
                for (int c4 = 0; c4 < 4; c4++) {
                    float4 v = *(const float4*)(xrow + k0 + c4 * 4);
                    tmp[c4 * 4 + 0] = f2b(v.x); tmp[c4 * 4 + 1] = f2b(v.y);
                    tmp[c4 * 4 + 2] = f2b(v.z); tmp[c4 * 4 + 3] = f2b(v.w);
                }
            } else {
#pragma unroll
                for (int j = 0; j < 16; j++) tmp[j] = 0;
            }
            *(uint4*)(&As[srow * 32 + shalf * 16]) = ((const uint4*)tmp)[0];
            *(uint4*)(&As[srow * 32 + shalf * 16 + 8]) = ((const uint4*)tmp)[1];
            *(uint4*)(&Bs[srow * 32 + shalf * 16]) = *(const uint4*)(brow + k0);
            *(uint4*)(&Bs[srow * 32 + shalf * 16 + 8]) = *(const uint4*)(brow + k0 + 8);
            __syncthreads();
            bfrag af[4], bf[4];
#pragma unroll
            for (int i = 0; i < 4; i++) {
                af[i] = *(const bfrag*)(&As[(wr * 64 + i * 16 + r) * 32 + q * 8]);
                bf[i] = *(const bfrag*)(&Bs[(wc * 64 + i * 16 + r) * 32 + q * 8]);
            }
#pragma unroll
            for (int mi = 0; mi < 4; mi++)
#pragma unroll
                for (int ni = 0; ni < 4; ni++)
                    acc[mi][ni] = mfma16(af[mi], bf[ni], acc[mi][ni]);
            __syncthreads();
        }
#pragma unroll
        for (int mi = 0; mi < 4; mi++)
#pragma unroll
            for (int ni = 0; ni < 4; ni++) {
                int col = n0 + wc * 64 + ni * 16 + r;
                float bias = b1[(size_t)e * F_HID + col];
#pragma unroll
                for (int i = 0; i < 4; i++) {
                    int m = m0 + wr * 64 + mi * 16 + q * 4 + i;
                    if (m < Cl) {
                        float v = acc[mi][ni][i] + bias;
                        h[(size_t)(lo - P0 + m) * F_HID + col] = f2b(v > 0.f ? v : 0.f);
                    }
                }
            }
    }
}

// ---------------------------------------------------------------- FFN2 GEMM (split-K=2)
// out[tok] += g*(h[p-P0] . w2t[e]^T + b2[e]) via fp32 atomics.
__global__ __launch_bounds__(256) void moe_ffn2_kernel(
    const u16* __restrict__ h, const u16* __restrict__ w2t, const float* __restrict__ b2,
    const int* __restrict__ plist, const float* __restrict__ pg,
    const int* __restrict__ cnt, const int* __restrict__ off,
    float* __restrict__ out, int P0, int P1)
{
    __shared__ __align__(16) u16 As[128 * 32];
    __shared__ __align__(16) u16 Bs[128 * 32];
    const int e = blockIdx.z;
    int lo = off[e], hi = lo + cnt[e];
    if (lo < P0) lo = P0;
    if (hi > P1) hi = P1;
    const int Cl = hi - lo;
    if (Cl <= 0) return;
    const int nt = blockIdx.x % 6, kz = blockIdx.x / 6;
    const int n0 = nt * 128;
    const int kbeg = kz * (F_HID / 2), kend = kbeg + F_HID / 2;
    const int tid = threadIdx.x;
    const int lane = tid & 63, wave = tid >> 6;
    const int wr = wave >> 1, wc = wave & 1;
    const int q = lane >> 4, r = lane & 15;
    const int srow = tid >> 1, shalf = tid & 1;

    const u16* brow = w2t + ((size_t)e * D_EMB + n0 + srow) * F_HID + shalf * 16;

    for (int m0 = blockIdx.y * 128; m0 < Cl; m0 += gridDim.y * 128) {
        f32x4 acc[4][4] = {};
        const bool vrow = (m0 + srow) < Cl;
        const u16* arow = h + (size_t)(lo - P0 + m0 + srow) * F_HID + shalf * 16;

        for (int k0 = kbeg; k0 < kend; k0 += 32) {
            uint4 a0 = make_uint4(0, 0, 0, 0), a1 = make_uint4(0, 0, 0, 0);
            if (vrow) {
                a0 = *(const uint4*)(arow + k0);
                a1 = *(const uint4*)(arow + k0 + 8);
            }
            *(uint4*)(&As[srow * 32 + shalf * 16]) = a0;
            *(uint4*)(&As[srow * 32 + shalf * 16 + 8]) = a1;
            *(uint4*)(&Bs[srow * 32 + shalf * 16]) = *(const uint4*)(brow + k0);
            *(uint4*)(&Bs[srow * 32 + shalf * 16 + 8]) = *(const uint4*)(brow + k0 + 8);
            __syncthreads();
            bfrag af[4], bf[4];
#pragma unroll
            for (int i = 0; i < 4; i++) {
                af[i] = *(const bfrag*)(&As[(wr * 64 + i * 16 + r) * 32 + q * 8]);
                bf[i] = *(const bfrag*)(&Bs[(wc * 64 + i * 16 + r) * 32 + q * 8]);
            }
#pragma unroll
            for (int mi = 0; mi < 4; mi++)
#pragma unroll
                for (int ni = 0; ni < 4; ni++)
                    acc[mi][ni] = mfma16(af[mi], bf[ni], acc[mi][ni]);
            __syncthreads();
        }
#pragma unroll
        for (int mi = 0; mi < 4; mi++)
#pragma unroll
            for (int ni = 0; ni < 4; ni++) {
                int col = n0 + wc * 64 + ni * 16 + r;
                float bias = (kz == 0) ? b2[(size_t)e * D_EMB + col] : 0.f;
#pragma unroll
                for (int i = 0; i < 4; i++) {
                    int m = m0 + wr * 64 + mi * 16 + q * 4 + i;
                    if (m < Cl) {
                        int p = lo + m;
                        int tok = plist[p];
                        atomicAdd(&out[(size_t)tok * D_EMB + col],
                                  pg[p] * (acc[mi][ni][i] + bias));
                    }
                }
            }
    }
}

// ---------------------------------------------------------------- fallback fused FFN (fp32)
#define XSTR 776
#define HSTR 3080
#define BMF 8
__global__ __launch_bounds__(256) void moe_ffn_fused_f32(
    const float* __restrict__ x,
    const float* __restrict__ w1, const float* __restrict__ b1,
    const float* __restrict__ w2, const float* __restrict__ b2,
    const int* __restrict__ plist, const float* __restrict__ pg,
    const int* __restrict__ cnt, const int* __restrict__ off,
    float* __restrict__ out)
{
    __shared__ __align__(16) u16 xs[BMF * XSTR];
    __shared__ __align__(16) u16 hs[BMF * HSTR];
    const int e = blockIdx.x;
    const int Cl = cnt[e];
    if (Cl <= 0) return;
    const int O = off[e];
    const int tid = threadIdx.x;
    for (int t0 = blockIdx.y * BMF; t0 < Cl; t0 += gridDim.y * BMF) {
        for (int ci = tid; ci < BMF * 192; ci += 256) {
            int row = ci / 192, c = ci - row * 192;
            float4 v = make_float4(0.f, 0.f, 0.f, 0.f);
            if (t0 + row < Cl) {
                int tok = plist[O + t0 + row];
                v = *(const float4*)(x + (size_t)tok * D_EMB + c * 4);
            }
            u16* d = &xs[row * XSTR + c * 4];
            d[0] = f2b(v.x); d[1] = f2b(v.y); d[2] = f2b(v.z); d[3] = f2b(v.w);
        }
        __syncthreads();
        for (int wi = tid; wi < BMF * 768; wi += 256) {
            int row = wi / 768, nc = wi - row * 768;
            int n0 = nc * 4;
            float a0 = 0, a1 = 0, a2 = 0, a3 = 0;
            const float* wp = w1 + (size_t)e * D_EMB * F_HID + n0;
            const u16* xr = &xs[row * XSTR];
            for (int k = 0; k < D_EMB; k++) {
                float4 wv = *(const float4*)(wp + (size_t)k * F_HID);
                float xv = b2f(xr[k]);
                a0 += xv * wv.x; a1 += xv * wv.y; a2 += xv * wv.z; a3 += xv * wv.w;
            }
            const float* bp = b1 + (size_t)e * F_HID + n0;
            u16* hp = &hs[row * HSTR + n0];
            float v;
            v = a0 + bp[0]; hp[0] = f2b(v > 0.f ? v : 0.f);
            v = a1 + bp[1]; hp[1] = f2b(v > 0.f ? v : 0.f);
            v = a2 + bp[2]; hp[2] = f2b(v > 0.f ? v : 0.f);
            v = a3 + bp[3]; hp[3] = f2b(v > 0.f ? v : 0.f);
        }
        __syncthreads();
        for (int wi = tid; wi < BMF * 192; wi += 256) {
            int row = wi / 192, nc = wi - row * 192;
            int n0 = nc * 4;
            float a0 = 0, a1 = 0, a2 = 0, a3 = 0;
            const float* wp = w2 + (size_t)e * F_HID * D_EMB + n0;
            const u16* hr = &hs[row * HSTR];
            for (int k = 0; k < F_HID; k++) {
                float4 wv = *(const float4*)(wp + (size_t)k * D_EMB);
                float hv = b2f(hr[k]);
                a0 += hv * wv.x; a1 += hv * wv.y; a2 += hv * wv.z; a3 += hv * wv.w;
            }
            if (t0 + row < Cl) {
                int p = O + t0 + row;
                int tok = plist[p];
                float g = pg[p];
                const float* bp = b2 + (size_t)e * D_EMB + n0;
                float* op = out + (size_t)tok * D_EMB + n0;
                atomicAdd(&op[0], g * (a0 + bp[0]));
                atomicAdd(&op[1], g * (a1 + bp[1]));
                atomicAdd(&op[2], g * (a2 + bp[2]));
                atomicAdd(&op[3], g * (a3 + bp[3]));
            }
        }
        __syncthreads();
    }
}

// ---------------------------------------------------------------- launch
extern "C" void kernel_launch(void* const* d_in, const int* in_sizes, int n_in,
                              void* d_out, int out_size, void* d_ws, size_t ws_size,
                              hipStream_t stream) {
    const float* x     = (const float*)d_in[0];
    const float* noise = (const float*)d_in[1];
    const float* Wg    = (const float*)d_in[2];
    const float* bg    = (const float*)d_in[3];
    const float* Wn    = (const float*)d_in[4];
    const float* bn    = (const float*)d_in[5];
    const float* W1    = (const float*)d_in[6];
    const float* b1    = (const float*)d_in[7];
    const float* W2    = (const float*)d_in[8];
    const float* b2    = (const float*)d_in[9];
    float* out = (float*)d_out;

    // workspace layout
    char* ws = (char*)d_ws;
    int*   cnt    = (int*)(ws + 0);
    int*   off    = (int*)(ws + 256);
    int*   cursor = (int*)(ws + 512);
    int*   tk_e   = (int*)(ws + 1024);      // 32768 B
    float* tk_g   = (float*)(ws + 33792);   // 32768 B
    int*   plist  = (int*)(ws + 66560);     // 32768 B
    float* pg     = (float*)(ws + 99328);   // 32768 B
    const size_t W1T_OFF = 135168;                        // 8*3072*768*2 = 37748736
    const size_t W2T_OFF = W1T_OFF + 37748736;            // 37748736
    const size_t H_OFF   = W2T_OFF + 37748736;            // h: pchunk*3072*2
    u16* w1t = (u16*)(ws + W1T_OFF);
    u16* w2t = (u16*)(ws + W2T_OFF);
    u16* h   = (u16*)(ws + H_OFF);

    // largest h chunk that fits (0 => fallback path). Depends only on ws_size.
    int pchunk = 0;
    for (int p = N_PAIR; p >= 128; p >>= 1) {
        if (H_OFF + (size_t)p * F_HID * 2 <= ws_size) { pchunk = p; break; }
    }

    moe_init_kernel<<<dim3(1), dim3(64), 0, stream>>>(cnt);
    moe_zero_kernel<<<dim3(3072), dim3(256), 0, stream>>>((uint4*)out);
    moe_router_f32<<<dim3(N_TOK / 4), dim3(256), 0, stream>>>(
        x, noise, Wg, bg, Wn, bn, tk_e, tk_g, cnt);
    moe_offsets_kernel<<<dim3(1), dim3(64), 0, stream>>>(cnt, off, cursor);
    moe_scatter_kernel<<<dim3(N_PAIR / 256), dim3(256), 0, stream>>>(
        tk_e, tk_g, cursor, plist, pg);

    if (pchunk > 0) {
        // fast path: MFMA grouped GEMMs on pre-transposed bf16 weights
        moe_transcvt_kernel<<<dim3(F_HID / 32, D_EMB / 32, 8), dim3(256), 0, stream>>>(
            W1, w1t, D_EMB, F_HID);   // [e][768][3072] -> [e][3072][768]
        moe_transcvt_kernel<<<dim3(D_EMB / 32, F_HID / 32, 8), dim3(256), 0, stream>>>(
            W2, w2t, F_HID, D_EMB);   // [e][3072][768] -> [e][768][3072]
        const int gy = (pchunk >= 2048) ? 16 : (pchunk / 128);
        for (int c = 0; c < N_PAIR / pchunk; c++) {
            int P0 = c * pchunk, P1 = P0 + pchunk;
            moe_ffn1_kernel<<<dim3(F_HID / 128, gy, 8), dim3(256), 0, stream>>>(
                x, w1t, b1, plist, cnt, off, h, P0, P1);
            moe_ffn2_kernel<<<dim3(12, gy, 8), dim3(256), 0, stream>>>(
                h, w2t, b2, plist, pg, cnt, off, out, P0, P1);
        }
    } else {
        moe_ffn_fused_f32<<<dim3(8, 192), dim3(256), 0, stream>>>(
            x, W1, b1, W2, b2, plist, pg, cnt, off, out);
    }
    (void)in_sizes; (void)n_in; (void)out_size;
}